// Round 2
// baseline (116.309 us; speedup 1.0000x reference)
//
#include <hip/hip_runtime.h>
#include <stdint.h>

#define KCODES 22          // emb rows (codes 0..21)
#define KW     11          // packed uint32 words per cycle (2 x u16 counts each)

// ---------------- kernel 1: zero the packed histogram ----------------
__global__ void zero_hist(uint32_t* __restrict__ cnt, int nwords4) {
    int i = blockIdx.x * blockDim.x + threadIdx.x;
    if (i < nwords4) {
        ((uint4*)cnt)[i] = make_uint4(0u, 0u, 0u, 0u);
    }
}

// ---------------- kernel 2: histogram over (cycle, code) ----------------
// a2c: [2, E] row-major int32.  x: [N] int32 codes in [0,22).
__global__ void count_edges(const int* __restrict__ a2c,
                            const int* __restrict__ x,
                            uint32_t* __restrict__ cnt, int E) {
    int e = blockIdx.x * blockDim.x + threadIdx.x;
    if (e < E) {
        int atom = a2c[e];        // coalesced
        int cyc  = a2c[E + e];    // coalesced
        int code = x[atom];       // random gather, 400 KB -> L2-resident
        // two 16-bit counters per word; avg 6 edges/cycle -> no overflow risk
        atomicAdd(&cnt[cyc * KW + (code >> 1)], 1u << ((code & 1) * 16));
    }
}

// ---------------- kernel 3: out[c][:] = sum_k cnt[c][k] * emb[k][:] ----------------
// 256 threads: 8 cycles per block-iteration, 32 lanes x float4 cover D=128.
__global__ __launch_bounds__(256) void expand_out(
        const uint32_t* __restrict__ cnt,
        const float* __restrict__ emb,
        float* __restrict__ out, int num_seg) {
    __shared__ float4 semb[KCODES][32];   // 22 x 128 floats = 11 KB
    for (int i = threadIdx.x; i < KCODES * 32; i += blockDim.x) {
        semb[i >> 5][i & 31] = ((const float4*)emb)[i];
    }
    __syncthreads();

    const int d4  = threadIdx.x & 31;   // which float4 of the 128-wide row
    const int sub = threadIdx.x >> 5;   // 0..7: cycle within the block tile

    int c = blockIdx.x * 8 + sub;
    if (c < num_seg) {
        const uint32_t* crow = cnt + (size_t)c * KW;
        float4 acc = make_float4(0.f, 0.f, 0.f, 0.f);
#pragma unroll
        for (int w = 0; w < KW; ++w) {
            uint32_t word = crow[w];           // 32 lanes same addr -> broadcast
            float c0 = (float)(word & 0xFFFFu);
            float c1 = (float)(word >> 16);
            float4 e0 = semb[2 * w][d4];
            float4 e1 = semb[2 * w + 1][d4];
            acc.x += c0 * e0.x + c1 * e1.x;
            acc.y += c0 * e0.y + c1 * e1.y;
            acc.z += c0 * e0.z + c1 * e1.z;
            acc.w += c0 * e0.w + c1 * e1.w;
        }
        ((float4*)out)[(size_t)c * 32 + d4] = acc;  // coalesced 512B/row
    }
}

// ---------------- fallback path (only if ws too small): direct scatter ----------------
__global__ void zero_out_f4(float4* __restrict__ out, int n4) {
    int i = blockIdx.x * blockDim.x + threadIdx.x;
    if (i < n4) out[i] = make_float4(0.f, 0.f, 0.f, 0.f);
}

__global__ void scatter_edges(const int* __restrict__ a2c,
                              const int* __restrict__ x,
                              const float* __restrict__ emb,
                              float* __restrict__ out, int E) {
    // one wave-half (32 lanes) per edge would be overkill; use 4 lanes/edge:
    // thread t handles edge e = t/32, dims [ (t%32)*4 .. +3 ]
    int t = blockIdx.x * blockDim.x + threadIdx.x;
    int e = t >> 5;
    int d = (t & 31) * 4;
    if (e < E) {
        int atom = a2c[e];
        int cyc  = a2c[E + e];
        int code = x[atom];
        const float4 ev = ((const float4*)emb)[code * 32 + (d >> 2)];
        float* o = out + (size_t)cyc * 128 + d;
        atomicAdd(o + 0, ev.x);
        atomicAdd(o + 1, ev.y);
        atomicAdd(o + 2, ev.z);
        atomicAdd(o + 3, ev.w);
    }
}

extern "C" void kernel_launch(void* const* d_in, const int* in_sizes, int n_in,
                              void* d_out, int out_size, void* d_ws, size_t ws_size,
                              hipStream_t stream) {
    const int*   x    = (const int*)d_in[0];      // [N] codes
    const int*   a2c  = (const int*)d_in[1];      // [2, E]
    const float* emb  = (const float*)d_in[2];    // [22, 128]
    float*       out  = (float*)d_out;

    const int E       = in_sizes[1] / 2;          // 600000
    const int D       = in_sizes[2] / KCODES;     // 128
    const int num_seg = out_size / D;             // 100000

    const size_t need = (size_t)num_seg * KW * sizeof(uint32_t);  // ~4.4 MB

    if (ws_size >= need) {
        uint32_t* cnt = (uint32_t*)d_ws;
        const int nwords  = num_seg * KW;
        const int nwords4 = (nwords + 3) / 4;

        zero_hist<<<(nwords4 + 255) / 256, 256, 0, stream>>>(cnt, nwords4);
        count_edges<<<(E + 255) / 256, 256, 0, stream>>>(a2c, x, cnt, E);
        expand_out<<<(num_seg + 7) / 8, 256, 0, stream>>>(cnt, emb, out, num_seg);
    } else {
        // fallback: zero output, then atomic scatter of embeddings
        int n4 = out_size / 4;
        zero_out_f4<<<(n4 + 255) / 256, 256, 0, stream>>>((float4*)out, n4);
        long long threads = (long long)E * 32;
        int blocks = (int)((threads + 255) / 256);
        scatter_edges<<<blocks, 256, 0, stream>>>(a2c, x, emb, out, E);
    }
    (void)n_in; (void)D;
}

// Round 3
// 114.461 us; speedup vs baseline: 1.0161x; 1.0161x over previous
//
#include <hip/hip_runtime.h>
#include <stdint.h>

#define KCODES 22          // emb rows (codes 0..21)
#define KW     12          // padded uint32 words per cycle row (11 used) -> 48B, 16B-aligned

// ---------------- kernel: histogram over (cycle, code), 4 edges/thread ----------------
__global__ void count_edges4(const int* __restrict__ a2c,
                             const int* __restrict__ x,
                             uint32_t* __restrict__ cnt, int E) {
    int i = blockIdx.x * blockDim.x + threadIdx.x;
    int E4 = E >> 2;
    if (i < E4) {
        int4 a = ((const int4*)a2c)[i];            // atoms, coalesced 16B
        int4 c = ((const int4*)(a2c + E))[i];      // cycles, coalesced 16B (E%4==0)
        uint32_t k0 = (uint32_t)x[a.x];
        uint32_t k1 = (uint32_t)x[a.y];
        uint32_t k2 = (uint32_t)x[a.z];
        uint32_t k3 = (uint32_t)x[a.w];
        atomicAdd(&cnt[(size_t)c.x * KW + (k0 >> 1)], 1u << ((k0 & 1) << 4));
        atomicAdd(&cnt[(size_t)c.y * KW + (k1 >> 1)], 1u << ((k1 & 1) << 4));
        atomicAdd(&cnt[(size_t)c.z * KW + (k2 >> 1)], 1u << ((k2 & 1) << 4));
        atomicAdd(&cnt[(size_t)c.w * KW + (k3 >> 1)], 1u << ((k3 & 1) << 4));
    }
}

__global__ void count_edges1(const int* __restrict__ a2c,
                             const int* __restrict__ x,
                             uint32_t* __restrict__ cnt, int E) {
    int e = blockIdx.x * blockDim.x + threadIdx.x;
    if (e < E) {
        int atom = a2c[e];
        int cyc  = a2c[E + e];
        uint32_t code = (uint32_t)x[atom];
        atomicAdd(&cnt[(size_t)cyc * KW + (code >> 1)], 1u << ((code & 1) << 4));
    }
}

// ---------------- kernel: out[c][:] = sum_k cnt[c][k] * emb[k][:] ----------------
// emb column slice lives in registers (22 x float4); no LDS, no barriers.
// 32 lanes cover D=128 as float4; 8 rows per block-iteration; grid-stride.
__global__ __launch_bounds__(256) void expand_out(
        const uint32_t* __restrict__ cnt,
        const float* __restrict__ emb,
        float* __restrict__ out, int num_seg) {
    const int d4  = threadIdx.x & 31;   // float4 column index
    const int sub = threadIdx.x >> 5;   // row-within-block 0..7

    float4 e[KCODES];
#pragma unroll
    for (int k = 0; k < KCODES; ++k)
        e[k] = ((const float4*)emb)[k * 32 + d4];   // L1-hot, once per thread

    for (int c = blockIdx.x * 8 + sub; c < num_seg; c += gridDim.x * 8) {
        const uint4* crow = (const uint4*)(cnt + (size_t)c * KW);
        uint4 w0 = crow[0], w1 = crow[1], w2 = crow[2];   // 32 lanes same line -> broadcast
        uint32_t wv[12] = {w0.x, w0.y, w0.z, w0.w,
                           w1.x, w1.y, w1.z, w1.w,
                           w2.x, w2.y, w2.z, w2.w};
        float4 acc = make_float4(0.f, 0.f, 0.f, 0.f);
#pragma unroll
        for (int w = 0; w < 11; ++w) {                    // 11 words = codes 0..21
            float c0 = (float)(wv[w] & 0xFFFFu);
            float c1 = (float)(wv[w] >> 16);
            float4 e0 = e[2 * w], e1 = e[2 * w + 1];
            acc.x = fmaf(c1, e1.x, fmaf(c0, e0.x, acc.x));
            acc.y = fmaf(c1, e1.y, fmaf(c0, e0.y, acc.y));
            acc.z = fmaf(c1, e1.z, fmaf(c0, e0.z, acc.z));
            acc.w = fmaf(c1, e1.w, fmaf(c0, e0.w, acc.w));
        }
        ((float4*)out)[(size_t)c * 32 + d4] = acc;        // coalesced 512B/row
    }
}

// ---------------- fallback (ws too small): zero + direct atomic scatter ----------------
__global__ void zero_out_f4(float4* __restrict__ out, int n4) {
    int i = blockIdx.x * blockDim.x + threadIdx.x;
    if (i < n4) out[i] = make_float4(0.f, 0.f, 0.f, 0.f);
}

__global__ void scatter_edges(const int* __restrict__ a2c,
                              const int* __restrict__ x,
                              const float* __restrict__ emb,
                              float* __restrict__ out, int E) {
    int t = blockIdx.x * blockDim.x + threadIdx.x;
    int e = t >> 5;
    int d = (t & 31) * 4;
    if (e < E) {
        int atom = a2c[e];
        int cyc  = a2c[E + e];
        int code = x[atom];
        const float4 ev = ((const float4*)emb)[code * 32 + (d >> 2)];
        float* o = out + (size_t)cyc * 128 + d;
        atomicAdd(o + 0, ev.x);
        atomicAdd(o + 1, ev.y);
        atomicAdd(o + 2, ev.z);
        atomicAdd(o + 3, ev.w);
    }
}

extern "C" void kernel_launch(void* const* d_in, const int* in_sizes, int n_in,
                              void* d_out, int out_size, void* d_ws, size_t ws_size,
                              hipStream_t stream) {
    const int*   x    = (const int*)d_in[0];      // [N] codes
    const int*   a2c  = (const int*)d_in[1];      // [2, E]
    const float* emb  = (const float*)d_in[2];    // [22, 128]
    float*       out  = (float*)d_out;

    const int E       = in_sizes[1] / 2;          // 600000
    const int D       = in_sizes[2] / KCODES;     // 128
    const int num_seg = out_size / D;             // 100000

    const size_t need = (size_t)num_seg * KW * sizeof(uint32_t);  // ~4.8 MB

    if (ws_size >= need) {
        uint32_t* cnt = (uint32_t*)d_ws;

        hipMemsetAsync(cnt, 0, need, stream);     // graph-capturable fill

        if ((E & 3) == 0) {
            int E4 = E >> 2;
            count_edges4<<<(E4 + 255) / 256, 256, 0, stream>>>(a2c, x, cnt, E);
        } else {
            count_edges1<<<(E + 255) / 256, 256, 0, stream>>>(a2c, x, cnt, E);
        }

        int blocks = (num_seg + 7) / 8;
        if (blocks > 2048) blocks = 2048;         // grid-stride, ~8 blocks/CU
        expand_out<<<blocks, 256, 0, stream>>>(cnt, emb, out, num_seg);
    } else {
        int n4 = out_size / 4;
        zero_out_f4<<<(n4 + 255) / 256, 256, 0, stream>>>((float4*)out, n4);
        long long threads = (long long)E * 32;
        int blocks = (int)((threads + 255) / 256);
        scatter_edges<<<blocks, 256, 0, stream>>>(a2c, x, emb, out, E);
    }
    (void)n_in; (void)D;
}

// Round 5
// 113.473 us; speedup vs baseline: 1.0250x; 1.0087x over previous
//
#include <hip/hip_runtime.h>
#include <stdint.h>

#define KCODES 22          // emb rows (codes 0..21)
#define KW     12          // padded uint32 words per cycle row (11 used) -> 48B, 16B-aligned

// Clang vector types (nontemporal builtins reject HIP_vector_type wrappers)
typedef int   int2v   __attribute__((ext_vector_type(2)));
typedef float float4v __attribute__((ext_vector_type(4)));

// ---------------- kernel: histogram over (cycle, code), 2 edges/thread ----------------
// a2c: [2, E] row-major int32.  x: [N] int32 codes in [0,22).
__global__ void count_edges2(const int* __restrict__ a2c,
                             const int* __restrict__ x,
                             uint32_t* __restrict__ cnt, int E) {
    int i = blockIdx.x * blockDim.x + threadIdx.x;
    int E2 = E >> 1;
    if (i < E2) {
        int2v a = __builtin_nontemporal_load(&((const int2v*)a2c)[i]);        // atoms
        int2v c = __builtin_nontemporal_load(&((const int2v*)(a2c + E))[i]);  // cycles
        uint32_t k0 = (uint32_t)x[a.x];   // random gather, 400 KB -> L2-resident
        uint32_t k1 = (uint32_t)x[a.y];
        atomicAdd(&cnt[(size_t)c.x * KW + (k0 >> 1)], 1u << ((k0 & 1) << 4));
        atomicAdd(&cnt[(size_t)c.y * KW + (k1 >> 1)], 1u << ((k1 & 1) << 4));
    }
}

__global__ void count_edges1(const int* __restrict__ a2c,
                             const int* __restrict__ x,
                             uint32_t* __restrict__ cnt, int E) {
    int e = blockIdx.x * blockDim.x + threadIdx.x;
    if (e < E) {
        int atom = a2c[e];
        int cyc  = a2c[E + e];
        uint32_t code = (uint32_t)x[atom];
        atomicAdd(&cnt[(size_t)cyc * KW + (code >> 1)], 1u << ((code & 1) << 4));
    }
}

// ---------------- kernel: out[c][:] = sum_k cnt[c][k] * emb[k][:] ----------------
// emb column slice in registers (22 x float4); no LDS, no barriers.
// 32 lanes cover D=128 as float4; 8 rows per block-iteration; grid-stride.
__global__ __launch_bounds__(256) void expand_out(
        const uint32_t* __restrict__ cnt,
        const float* __restrict__ emb,
        float* __restrict__ out, int num_seg) {
    const int d4  = threadIdx.x & 31;   // float4 column index
    const int sub = threadIdx.x >> 5;   // row-within-block 0..7

    float4v e[KCODES];
#pragma unroll
    for (int k = 0; k < KCODES; ++k)
        e[k] = ((const float4v*)emb)[k * 32 + d4];   // 11 KB table, L1/L2-hot

    for (int c = blockIdx.x * 8 + sub; c < num_seg; c += gridDim.x * 8) {
        const uint4* crow = (const uint4*)(cnt + (size_t)c * KW);
        uint4 w0 = crow[0], w1 = crow[1], w2 = crow[2];   // same line across lanes -> broadcast
        uint32_t wv[12] = {w0.x, w0.y, w0.z, w0.w,
                           w1.x, w1.y, w1.z, w1.w,
                           w2.x, w2.y, w2.z, w2.w};
        float4v acc = (float4v)(0.f);
#pragma unroll
        for (int w = 0; w < 11; ++w) {                    // 11 words = codes 0..21
            float c0 = (float)(wv[w] & 0xFFFFu);
            float c1 = (float)(wv[w] >> 16);
            float4v e0 = e[2 * w], e1 = e[2 * w + 1];
            acc.x = fmaf(c1, e1.x, fmaf(c0, e0.x, acc.x));
            acc.y = fmaf(c1, e1.y, fmaf(c0, e0.y, acc.y));
            acc.z = fmaf(c1, e1.z, fmaf(c0, e0.z, acc.z));
            acc.w = fmaf(c1, e1.w, fmaf(c0, e0.w, acc.w));
        }
        // output is written once and never re-read -> bypass L2 with NT store
        __builtin_nontemporal_store(acc, &((float4v*)out)[(size_t)c * 32 + d4]);
    }
}

// ---------------- fallback (ws too small): zero + direct atomic scatter ----------------
__global__ void zero_out_f4(float4* __restrict__ out, int n4) {
    int i = blockIdx.x * blockDim.x + threadIdx.x;
    if (i < n4) out[i] = make_float4(0.f, 0.f, 0.f, 0.f);
}

__global__ void scatter_edges(const int* __restrict__ a2c,
                              const int* __restrict__ x,
                              const float* __restrict__ emb,
                              float* __restrict__ out, int E) {
    int t = blockIdx.x * blockDim.x + threadIdx.x;
    int e = t >> 5;
    int d = (t & 31) * 4;
    if (e < E) {
        int atom = a2c[e];
        int cyc  = a2c[E + e];
        int code = x[atom];
        const float4 ev = ((const float4*)emb)[code * 32 + (d >> 2)];
        float* o = out + (size_t)cyc * 128 + d;
        atomicAdd(o + 0, ev.x);
        atomicAdd(o + 1, ev.y);
        atomicAdd(o + 2, ev.z);
        atomicAdd(o + 3, ev.w);
    }
}

extern "C" void kernel_launch(void* const* d_in, const int* in_sizes, int n_in,
                              void* d_out, int out_size, void* d_ws, size_t ws_size,
                              hipStream_t stream) {
    const int*   x    = (const int*)d_in[0];      // [N] codes
    const int*   a2c  = (const int*)d_in[1];      // [2, E]
    const float* emb  = (const float*)d_in[2];    // [22, 128]
    float*       out  = (float*)d_out;

    const int E       = in_sizes[1] / 2;          // 600000
    const int D       = in_sizes[2] / KCODES;     // 128
    const int num_seg = out_size / D;             // 100000

    const size_t need = (size_t)num_seg * KW * sizeof(uint32_t);  // ~4.8 MB

    if (ws_size >= need) {
        uint32_t* cnt = (uint32_t*)d_ws;

        (void)hipMemsetAsync(cnt, 0, need, stream);   // graph-capturable fill, ~1 us

        if ((E & 1) == 0) {
            int E2 = E >> 1;
            count_edges2<<<(E2 + 255) / 256, 256, 0, stream>>>(a2c, x, cnt, E);
        } else {
            count_edges1<<<(E + 255) / 256, 256, 0, stream>>>(a2c, x, cnt, E);
        }

        // 1024 blocks ~= co-residency at ~110 VGPR; halves emb preload traffic vs 2048
        int blocks = (num_seg + 7) / 8;
        if (blocks > 1024) blocks = 1024;
        expand_out<<<blocks, 256, 0, stream>>>(cnt, emb, out, num_seg);
    } else {
        int n4 = out_size / 4;
        zero_out_f4<<<(n4 + 255) / 256, 256, 0, stream>>>((float4*)out, n4);
        long long threads = (long long)E * 32;
        int blocks = (int)((threads + 255) / 256);
        scatter_edges<<<blocks, 256, 0, stream>>>(a2c, x, emb, out, E);
    }
    (void)n_in; (void)D;
}